// Round 1
// baseline (2523.494 us; speedup 1.0000x reference)
//
#include <hip/hip_runtime.h>
#include <math.h>

// ---- problem constants ----
static constexpr int B_   = 2;
static constexpr int DM_  = 256;
static constexpr int M_   = 8;
static constexpr int LV_  = 4;
static constexpr int P_   = 4;
static constexpr int NL_  = 2;
static constexpr int DFF_ = 1024;
static constexpr int DH_  = 32;    // DM/M
static constexpr int LEN_ = 18720; // sum of level sizes
static constexpr int NQ_  = B_ * LEN_; // 37440  (divisible by 64)

// level geometry
// SHAPES = [(16,32,32),(8,16,16),(4,8,8),(2,4,4)]  sizes 16384,2048,256,32

// ============ flatten: [B,DM,S] -> rows of src/[pos+lemb] ============
__global__ void k_flatten(const float* __restrict__ si, const float* __restrict__ pi,
                          const float* __restrict__ lemb, int l, int S, int off,
                          float* __restrict__ src, float* __restrict__ pos) {
    int c = threadIdx.x;          // 0..255 channel
    int t = blockIdx.x;           // b*S + s
    int b = t / S, s = t - b * S;
    float sv = si[(b * DM_ + c) * S + s];
    float pv = pi[(b * DM_ + c) * S + s] + lemb[l * DM_ + c];
    int row = b * LEN_ + off + s;
    src[row * DM_ + c] = sv;
    pos[row * DM_ + c] = pv;
}

// ============ elementwise add (q = src + lvl_pos) ============
__global__ void k_add(const float4* __restrict__ a, const float4* __restrict__ b,
                      float4* __restrict__ o, int n4) {
    for (int i = blockIdx.x * blockDim.x + threadIdx.x; i < n4; i += gridDim.x * blockDim.x) {
        float4 x = a[i], y = b[i];
        o[i] = make_float4(x.x + y.x, x.y + y.y, x.z + y.z, x.w + y.w);
    }
}

// ============ fp32 GEMM: C[NQ x N] = A[NQ x K] @ W[K x N] + bias, opt relu ====
// BM=64, BN=128, BK=16; 256 threads; each thread 4x8 outputs.
__global__ __launch_bounds__(256) void k_gemm(const float* __restrict__ A,
                                              const float* __restrict__ W,
                                              const float* __restrict__ bias,
                                              float* __restrict__ C,
                                              int K, int N, int relu) {
    __shared__ float As[16][68];    // [k][row], pad 68 to break write conflicts
    __shared__ float Ws[16][128];   // [k][col]
    int tid = threadIdx.x;
    int tx = tid & 15, ty = tid >> 4;
    int row0 = blockIdx.x * 64;
    int col0 = blockIdx.y * 128;
    int lr = tid >> 2, lk = (tid & 3) * 4;     // A tile load: row lr, k-quad lk
    int wk = tid >> 4, wc = (tid & 15) * 4;    // W tile load: k-row wk, col-quad wc

    float acc[4][8];
#pragma unroll
    for (int i = 0; i < 4; ++i)
#pragma unroll
        for (int j = 0; j < 8; ++j) acc[i][j] = 0.f;

    for (int kt = 0; kt < K; kt += 16) {
        float4 av = *(const float4*)&A[(size_t)(row0 + lr) * K + kt + lk];
        float4 wv0 = *(const float4*)&W[(size_t)(kt + wk) * N + col0 + wc];
        float4 wv1 = *(const float4*)&W[(size_t)(kt + wk) * N + col0 + wc + 64];
        As[lk + 0][lr] = av.x;
        As[lk + 1][lr] = av.y;
        As[lk + 2][lr] = av.z;
        As[lk + 3][lr] = av.w;
        *(float4*)&Ws[wk][wc] = wv0;
        *(float4*)&Ws[wk][wc + 64] = wv1;
        __syncthreads();
#pragma unroll
        for (int k = 0; k < 16; ++k) {
            float4 a4 = *(const float4*)&As[k][ty * 4];
            float4 b40 = *(const float4*)&Ws[k][tx * 8];
            float4 b41 = *(const float4*)&Ws[k][tx * 8 + 4];
            float a[4] = {a4.x, a4.y, a4.z, a4.w};
            float b[8] = {b40.x, b40.y, b40.z, b40.w, b41.x, b41.y, b41.z, b41.w};
#pragma unroll
            for (int i = 0; i < 4; ++i)
#pragma unroll
                for (int j = 0; j < 8; ++j) acc[i][j] = fmaf(a[i], b[j], acc[i][j]);
        }
        __syncthreads();
    }
#pragma unroll
    for (int i = 0; i < 4; ++i) {
        int row = row0 + ty * 4 + i;
#pragma unroll
        for (int j = 0; j < 8; ++j) {
            int col = col0 + tx * 8 + j;
            float v = acc[i][j] + bias[col];
            if (relu) v = fmaxf(v, 0.f);
            C[(size_t)row * N + col] = v;
        }
    }
}

// ============ fused softmax + trilinear deformable sampling ============
// grid = NQ blocks, 256 threads; thread = (m = tid>>5, c = tid&31)
__global__ __launch_bounds__(256) void k_sample(const float* __restrict__ offp,
                                                const float* __restrict__ logit,
                                                const float* __restrict__ value,
                                                float* __restrict__ agg) {
    int row = blockIdx.x;
    int b = row / LEN_, qi = row - b * LEN_;
    __shared__ float so[384];
    __shared__ float sa[128];
    int tid = threadIdx.x;
    if (tid < 128) sa[tid] = logit[(size_t)row * 128 + tid];
    for (int i = tid; i < 384; i += 256) so[i] = offp[(size_t)row * 384 + i];
    __syncthreads();
    if (tid < 8) {  // per-head softmax over LV*P=16
        float mx = -1e30f;
#pragma unroll
        for (int i = 0; i < 16; ++i) mx = fmaxf(mx, sa[tid * 16 + i]);
        float e[16], sm = 0.f;
#pragma unroll
        for (int i = 0; i < 16; ++i) { e[i] = expf(sa[tid * 16 + i] - mx); sm += e[i]; }
        float inv = 1.f / sm;
#pragma unroll
        for (int i = 0; i < 16; ++i) sa[tid * 16 + i] = e[i] * inv;
    }
    __syncthreads();

    // reference point from query's own level geometry
    int lq, s;
    if (qi < 16384)      { lq = 0; s = qi; }
    else if (qi < 18432) { lq = 1; s = qi - 16384; }
    else if (qi < 18688) { lq = 2; s = qi - 18432; }
    else                 { lq = 3; s = qi - 18688; }
    const int dD[4] = {16, 8, 4, 2}, dH[4] = {32, 16, 8, 4}, dW[4] = {32, 16, 8, 4};
    const int loff[4] = {0, 16384, 18432, 18688};
    int Dq = dD[lq], Hq = dH[lq], Wq = dW[lq];
    int zq = s / (Hq * Wq);
    int rr = s - zq * (Hq * Wq);
    int yq = rr / Wq, xq = rr - (rr / Wq) * Wq;
    float ref0 = (zq + 0.5f) / Dq, ref1 = (yq + 0.5f) / Hq, ref2 = (xq + 0.5f) / Wq;

    int m = tid >> 5, c = tid & 31;
    float acc = 0.f;
#pragma unroll
    for (int l = 0; l < 4; ++l) {
        const int D_ = dD[l], H_ = dH[l], W_ = dW[l];
        const float* vbase = value + (size_t)(b * LEN_ + loff[l]) * DM_ + m * DH_ + c;
#pragma unroll
        for (int p = 0; p < P_; ++p) {
            int oi = ((m * LV_ + l) * P_ + p) * 3;
            float loc0 = ref0 + so[oi + 0] / W_;
            float loc1 = ref1 + so[oi + 1] / H_;
            float loc2 = ref2 + so[oi + 2] / D_;
            float x = loc0 * W_ - 0.5f;
            float y = loc1 * H_ - 0.5f;
            float z = loc2 * D_ - 0.5f;
            float xf = floorf(x), yf = floorf(y), zf = floorf(z);
            float fx = x - xf, fy = y - yf, fz = z - zf;
            int x0 = (int)xf, y0 = (int)yf, z0 = (int)zf;
            float aw = sa[m * 16 + l * 4 + p];
            float pt = 0.f;
#pragma unroll
            for (int dz = 0; dz < 2; ++dz)
#pragma unroll
                for (int dy = 0; dy < 2; ++dy)
#pragma unroll
                    for (int dx = 0; dx < 2; ++dx) {
                        int xi = x0 + dx, yi = y0 + dy, zi = z0 + dz;
                        float w = (dx ? fx : 1.f - fx) * (dy ? fy : 1.f - fy) * (dz ? fz : 1.f - fz);
                        bool valid = (xi >= 0) & (xi < W_) & (yi >= 0) & (yi < H_) &
                                     (zi >= 0) & (zi < D_);
                        int xc = min(max(xi, 0), W_ - 1);
                        int yc = min(max(yi, 0), H_ - 1);
                        int zc = min(max(zi, 0), D_ - 1);
                        int idx = (zc * H_ + yc) * W_ + xc;
                        float v = vbase[(size_t)idx * DM_];
                        pt += valid ? w * v : 0.f;
                    }
            acc = fmaf(aw, pt, acc);
        }
    }
    agg[(size_t)row * DM_ + m * DH_ + c] = acc;
}

// ============ fused residual-add + LayerNorm (wave per row) ============
__global__ __launch_bounds__(256) void k_add_ln(const float* __restrict__ X,
                                                const float* __restrict__ R,
                                                const float* __restrict__ g,
                                                const float* __restrict__ bb,
                                                float* __restrict__ O) {
    int wid = threadIdx.x >> 6, lane = threadIdx.x & 63;
    int row = blockIdx.x * 4 + wid;
    float4 x = ((const float4*)&X[(size_t)row * DM_])[lane];
    float4 r = ((const float4*)&R[(size_t)row * DM_])[lane];
    float v[4] = {x.x + r.x, x.y + r.y, x.z + r.z, x.w + r.w};
    float sm = v[0] + v[1] + v[2] + v[3];
#pragma unroll
    for (int o = 32; o; o >>= 1) sm += __shfl_xor(sm, o, 64);
    float mu = sm * (1.f / 256.f);
    float q = 0.f;
#pragma unroll
    for (int i = 0; i < 4; ++i) { float d = v[i] - mu; q += d * d; }
#pragma unroll
    for (int o = 32; o; o >>= 1) q += __shfl_xor(q, o, 64);
    float inv = rsqrtf(q * (1.f / 256.f) + 1e-5f);
    int c0 = lane * 4;
    float4 gv = *(const float4*)&g[c0];
    float4 bv = *(const float4*)&bb[c0];
    float4 o4;
    o4.x = (v[0] - mu) * inv * gv.x + bv.x;
    o4.y = (v[1] - mu) * inv * gv.y + bv.y;
    o4.z = (v[2] - mu) * inv * gv.z + bv.z;
    o4.w = (v[3] - mu) * inv * gv.w + bv.w;
    ((float4*)&O[(size_t)row * DM_])[lane] = o4;
}

extern "C" void kernel_launch(void* const* d_in, const int* in_sizes, int n_in,
                              void* d_out, int out_size, void* d_ws, size_t ws_size,
                              hipStream_t stream) {
    const float* src_in[4] = {(const float*)d_in[0], (const float*)d_in[2],
                              (const float*)d_in[4], (const float*)d_in[6]};
    const float* pos_in[4] = {(const float*)d_in[1], (const float*)d_in[3],
                              (const float*)d_in[5], (const float*)d_in[7]};
    const float* lemb  = (const float*)d_in[8];
    const float* W_off = (const float*)d_in[9];
    const float* bOff  = (const float*)d_in[10];
    const float* W_att = (const float*)d_in[11];
    const float* bAtt  = (const float*)d_in[12];
    const float* W_val = (const float*)d_in[13];
    const float* bVal  = (const float*)d_in[14];
    const float* W_out = (const float*)d_in[15];
    const float* bOut  = (const float*)d_in[16];
    const float* ln1g  = (const float*)d_in[17];
    const float* ln1b  = (const float*)d_in[18];
    const float* W_ff1 = (const float*)d_in[19];
    const float* bFf1  = (const float*)d_in[20];
    const float* W_ff2 = (const float*)d_in[21];
    const float* bFf2  = (const float*)d_in[22];
    const float* ln2g  = (const float*)d_in[23];
    const float* ln2b  = (const float*)d_in[24];

    // workspace layout (floats): src | lvl_pos | q/out | big(1024/row)
    float* ws = (float*)d_ws;
    float* b_src = ws;
    float* b_pos = b_src + (size_t)NQ_ * DM_;
    float* b_q   = b_pos + (size_t)NQ_ * DM_;
    float* b_big = b_q + (size_t)NQ_ * DM_;
    float* b_valb = b_big;                          // NQ*256
    float* b_offb = b_big + (size_t)NQ_ * 256;      // NQ*384
    float* b_attb = b_offb + (size_t)NQ_ * 384;     // NQ*128
    float* b_agg  = b_attb + (size_t)NQ_ * 128;     // NQ*256
    float* b_ffh  = b_big;                          // NQ*1024 (aliases the 4 above)

    const int S[4]   = {16384, 2048, 256, 32};
    const int OFF[4] = {0, 16384, 18432, 18688};
    for (int l = 0; l < 4; ++l)
        k_flatten<<<dim3(B_ * S[l]), dim3(256), 0, stream>>>(
            src_in[l], pos_in[l], lemb, l, S[l], OFF[l], b_src, b_pos);

    for (int l = 0; l < NL_; ++l) {
        int n4 = NQ_ * DM_ / 4;
        k_add<<<dim3(2048), dim3(256), 0, stream>>>((const float4*)b_src,
                                                    (const float4*)b_pos,
                                                    (float4*)b_q, n4);
        k_gemm<<<dim3(NQ_ / 64, 256 / 128), 256, 0, stream>>>(
            b_src, W_val + (size_t)l * DM_ * DM_, bVal + l * DM_, b_valb, DM_, 256, 0);
        k_gemm<<<dim3(NQ_ / 64, 384 / 128), 256, 0, stream>>>(
            b_q, W_off + (size_t)l * DM_ * 384, bOff + l * 384, b_offb, DM_, 384, 0);
        k_gemm<<<dim3(NQ_ / 64, 128 / 128), 256, 0, stream>>>(
            b_q, W_att + (size_t)l * DM_ * 128, bAtt + l * 128, b_attb, DM_, 128, 0);
        k_sample<<<dim3(NQ_), 256, 0, stream>>>(b_offb, b_attb, b_valb, b_agg);
        k_gemm<<<dim3(NQ_ / 64, 256 / 128), 256, 0, stream>>>(
            b_agg, W_out + (size_t)l * DM_ * DM_, bOut + l * DM_, b_q, DM_, 256, 0);
        k_add_ln<<<dim3(NQ_ / 4), 256, 0, stream>>>(b_src, b_q, ln1g + l * DM_,
                                                    ln1b + l * DM_, b_src);
        k_gemm<<<dim3(NQ_ / 64, DFF_ / 128), 256, 0, stream>>>(
            b_src, W_ff1 + (size_t)l * DM_ * DFF_, bFf1 + l * DFF_, b_ffh, DM_, DFF_, 1);
        k_gemm<<<dim3(NQ_ / 64, 256 / 128), 256, 0, stream>>>(
            b_ffh, W_ff2 + (size_t)l * DFF_ * DM_, bFf2 + l * DM_, b_q, DFF_, 256, 0);
        float* dst = (l == NL_ - 1) ? (float*)d_out : b_src;
        k_add_ln<<<dim3(NQ_ / 4), 256, 0, stream>>>(b_src, b_q, ln2g + l * DM_,
                                                    ln2b + l * DM_, dst);
    }
}

// Round 2
// 960.834 us; speedup vs baseline: 2.6264x; 2.6264x over previous
//
#include <hip/hip_runtime.h>
#include <hip/hip_bf16.h>
#include <math.h>

typedef __attribute__((ext_vector_type(4))) float f32x4;
typedef __attribute__((ext_vector_type(8))) short bf16x8;

static constexpr int B_   = 2;
static constexpr int DM_  = 256;
static constexpr int LV_  = 4;
static constexpr int P_   = 4;
static constexpr int NL_  = 2;
static constexpr int DFF_ = 1024;
static constexpr int LEN_ = 18720;
static constexpr int NQ_  = 37440;           // B*LEN
static constexpr int NQP_ = 37504;           // padded to 128*293

__device__ __forceinline__ unsigned short f2bf(float x) {
    __hip_bfloat16 h = __float2bfloat16(x);
    return *reinterpret_cast<unsigned short*>(&h);
}

// ============ flatten: [B,DM,S] -> rows; src fp32+bf16, pos fp32 ============
__global__ void k_flatten(const float* __restrict__ si, const float* __restrict__ pi,
                          const float* __restrict__ lemb, int l, int S, int off,
                          float* __restrict__ src, unsigned short* __restrict__ srcbf,
                          float* __restrict__ pos) {
    int c = threadIdx.x;
    int t = blockIdx.x;
    int b = t / S, s = t - b * S;
    float sv = si[(size_t)(b * DM_ + c) * S + s];
    float pv = pi[(size_t)(b * DM_ + c) * S + s] + lemb[l * DM_ + c];
    size_t row = (size_t)b * LEN_ + off + s;
    src[row * DM_ + c] = sv;
    srcbf[row * DM_ + c] = f2bf(sv);
    pos[row * DM_ + c] = pv;
}

// ============ q = bf16(src + pos) ============
__global__ void k_addq(const float4* __restrict__ a, const float4* __restrict__ b,
                       ushort4* __restrict__ o, int n4) {
    for (int i = blockIdx.x * blockDim.x + threadIdx.x; i < n4; i += gridDim.x * blockDim.x) {
        float4 x = a[i], y = b[i];
        ushort4 r;
        r.x = f2bf(x.x + y.x); r.y = f2bf(x.y + y.y);
        r.z = f2bf(x.z + y.z); r.w = f2bf(x.w + y.w);
        o[i] = r;
    }
}

// ============ weight prep: W[K][N] fp32 -> Wt[N][K] bf16 ============
__global__ __launch_bounds__(256) void k_wprep(const float* __restrict__ W,
                                               unsigned short* __restrict__ Wt,
                                               int K, int N) {
    __shared__ float t[32][33];
    int n0 = blockIdx.x * 32, k0 = blockIdx.y * 32;
    int tx = threadIdx.x & 31, ty = threadIdx.x >> 5;
#pragma unroll
    for (int i = 0; i < 4; ++i)
        t[ty + i * 8][tx] = W[(size_t)(k0 + ty + i * 8) * N + n0 + tx];
    __syncthreads();
#pragma unroll
    for (int i = 0; i < 4; ++i)
        Wt[(size_t)(n0 + ty + i * 8) * K + k0 + tx] = f2bf(t[tx][ty + i * 8]);
}

// ============ bf16 MFMA GEMM: C[rows x N] = A[rows x K] @ Bt[N x K]^T + bias ===
// 128x128 tile, BK=32, 4 waves (2x2), each wave 64x64 via 4x4 16x16x32 MFMA.
// mode 0: write C fp32.  mode 1: relu + write Cbf bf16.
__global__ __launch_bounds__(256) void k_gemm(const unsigned short* __restrict__ A,
                                              const unsigned short* __restrict__ Bt,
                                              const float* __restrict__ bias,
                                              float* __restrict__ C,
                                              unsigned short* __restrict__ Cbf,
                                              int K, int N, int mode) {
    __shared__ unsigned short As[128 * 32];
    __shared__ unsigned short Bs[128 * 32];
    int tid = threadIdx.x;
    int w = tid >> 6, lane = tid & 63;
    int wr = w >> 1, wc = w & 1;
    int row0 = blockIdx.x * 128, col0 = blockIdx.y * 128;

    // staging: wave w covers chunks 2w, 2w+1; chunk = 16 rows of [r][32k] tile
    const unsigned short* gA = A + (size_t)(row0 + w * 32 + (lane >> 2)) * K + (lane & 3) * 8;
    const unsigned short* gB = Bt + (size_t)(col0 + w * 32 + (lane >> 2)) * K + (lane & 3) * 8;
    char* lA0 = (char*)As + w * 2048;
    char* lB0 = (char*)Bs + w * 2048;

    f32x4 acc[4][4];
#pragma unroll
    for (int m = 0; m < 4; ++m)
#pragma unroll
        for (int n = 0; n < 4; ++n) acc[m][n] = (f32x4){0.f, 0.f, 0.f, 0.f};

    int lr = lane & 15, lk = (lane >> 4) * 8;
    const unsigned short* pA = &As[(wr * 64 + lr) * 32 + lk];
    const unsigned short* pB = &Bs[(wc * 64 + lr) * 32 + lk];

    for (int kt = 0; kt < K; kt += 32) {
        __builtin_amdgcn_global_load_lds((const __attribute__((address_space(1))) void*)gA,
                                         (__attribute__((address_space(3))) void*)lA0, 16, 0, 0);
        __builtin_amdgcn_global_load_lds((const __attribute__((address_space(1))) void*)(gA + (size_t)16 * K),
                                         (__attribute__((address_space(3))) void*)(lA0 + 1024), 16, 0, 0);
        __builtin_amdgcn_global_load_lds((const __attribute__((address_space(1))) void*)gB,
                                         (__attribute__((address_space(3))) void*)lB0, 16, 0, 0);
        __builtin_amdgcn_global_load_lds((const __attribute__((address_space(1))) void*)(gB + (size_t)16 * K),
                                         (__attribute__((address_space(3))) void*)(lB0 + 1024), 16, 0, 0);
        gA += 32; gB += 32;
        __syncthreads();
        bf16x8 a[4], b[4];
#pragma unroll
        for (int m = 0; m < 4; ++m) a[m] = *(const bf16x8*)(pA + m * 16 * 32);
#pragma unroll
        for (int n = 0; n < 4; ++n) b[n] = *(const bf16x8*)(pB + n * 16 * 32);
#pragma unroll
        for (int m = 0; m < 4; ++m)
#pragma unroll
            for (int n = 0; n < 4; ++n)
                acc[m][n] = __builtin_amdgcn_mfma_f32_16x16x32_bf16(a[m], b[n], acc[m][n], 0, 0, 0);
        __syncthreads();
    }

    int fr = (lane >> 4) * 4, fc = lane & 15;
#pragma unroll
    for (int m = 0; m < 4; ++m) {
#pragma unroll
        for (int n = 0; n < 4; ++n) {
            int cc = col0 + wc * 64 + n * 16 + fc;
            float bv = bias[cc];
#pragma unroll
            for (int i = 0; i < 4; ++i) {
                int cr = row0 + wr * 64 + m * 16 + fr + i;
                float v = acc[m][n][i] + bv;
                if (mode) {
                    v = fmaxf(v, 0.f);
                    Cbf[(size_t)cr * N + cc] = f2bf(v);
                } else {
                    C[(size_t)cr * N + cc] = v;
                }
            }
        }
    }
}

// ============ fused softmax + trilinear sampling, two-phase ============
__global__ __launch_bounds__(256) void k_sample(const float* __restrict__ offp,
                                                const float* __restrict__ logit,
                                                const float* __restrict__ value,
                                                unsigned short* __restrict__ aggbf) {
    int row = blockIdx.x;
    int b = row / LEN_, qi = row - b * LEN_;
    __shared__ float2 sp[128][8];   // (weight, idx-as-bits)
    int tid = threadIdx.x;

    // reference point from query's own level
    int lq, s;
    if (qi < 16384)      { lq = 0; s = qi; }
    else if (qi < 18432) { lq = 1; s = qi - 16384; }
    else if (qi < 18688) { lq = 2; s = qi - 18432; }
    else                 { lq = 3; s = qi - 18688; }
    const int dD[4] = {16, 8, 4, 2}, dH[4] = {32, 16, 8, 4}, dW[4] = {32, 16, 8, 4};
    const int loff[4] = {0, 16384, 18432, 18688};
    int Dq = dD[lq], Hq = dH[lq], Wq = dW[lq];
    int zq = s / (Hq * Wq);
    int rr = s - zq * (Hq * Wq);
    int yq = rr / Wq, xq = rr - (rr / Wq) * Wq;
    float ref0 = (zq + 0.5f) / Dq, ref1 = (yq + 0.5f) / Hq, ref2 = (xq + 0.5f) / Wq;

    if (tid < 128) {
        int m = tid >> 4, l = (tid >> 2) & 3;
        float e = logit[(size_t)row * 128 + tid];
        float mx = e;
#pragma unroll
        for (int o = 1; o < 16; o <<= 1) mx = fmaxf(mx, __shfl_xor(mx, o, 16));
        float ex = expf(e - mx);
        float sm = ex;
#pragma unroll
        for (int o = 1; o < 16; o <<= 1) sm += __shfl_xor(sm, o, 16);
        float aw = ex / sm;

        const int D_ = dD[l], H_ = dH[l], W_ = dW[l];
        float o0 = offp[(size_t)row * 384 + tid * 3 + 0];
        float o1 = offp[(size_t)row * 384 + tid * 3 + 1];
        float o2 = offp[(size_t)row * 384 + tid * 3 + 2];
        float x = (ref0 + o0 / W_) * W_ - 0.5f;
        float y = (ref1 + o1 / H_) * H_ - 0.5f;
        float z = (ref2 + o2 / D_) * D_ - 0.5f;
        float xf = floorf(x), yf = floorf(y), zf = floorf(z);
        float fx = x - xf, fy = y - yf, fz = z - zf;
        int x0 = (int)xf, y0 = (int)yf, z0 = (int)zf;
        int vbase = (b * LEN_ + loff[l]) * DM_ + m * 32;
#pragma unroll
        for (int dz = 0; dz < 2; ++dz)
#pragma unroll
            for (int dy = 0; dy < 2; ++dy)
#pragma unroll
                for (int dx = 0; dx < 2; ++dx) {
                    int xi = x0 + dx, yi = y0 + dy, zi = z0 + dz;
                    float wgt = (dx ? fx : 1.f - fx) * (dy ? fy : 1.f - fy) * (dz ? fz : 1.f - fz);
                    bool valid = (xi >= 0) & (xi < W_) & (yi >= 0) & (yi < H_) &
                                 (zi >= 0) & (zi < D_);
                    int xc = min(max(xi, 0), W_ - 1);
                    int yc = min(max(yi, 0), H_ - 1);
                    int zc = min(max(zi, 0), D_ - 1);
                    int idx = (zc * H_ + yc) * W_ + xc;
                    float2 pr;
                    pr.x = valid ? aw * wgt : 0.f;
                    pr.y = __int_as_float(vbase + idx * DM_);
                    sp[tid][(dz << 2) | (dy << 1) | dx] = pr;
                }
    }
    __syncthreads();

    int m = tid >> 5, c = tid & 31;
    float acc = 0.f;
#pragma unroll
    for (int t = 0; t < 16; ++t) {
#pragma unroll
        for (int cr = 0; cr < 8; ++cr) {
            float2 wi = sp[m * 16 + t][cr];
            acc = fmaf(wi.x, value[__float_as_int(wi.y) + c], acc);
        }
    }
    aggbf[(size_t)row * DM_ + m * 32 + c] = f2bf(acc);
}

// ============ fused residual-add + LayerNorm; fp32 out + bf16 copy ============
__global__ __launch_bounds__(256) void k_add_ln(const float* __restrict__ X,
                                                const float* __restrict__ Rr,
                                                const float* __restrict__ g,
                                                const float* __restrict__ bb,
                                                float* __restrict__ O,
                                                unsigned short* __restrict__ Obf) {
    int wid = threadIdx.x >> 6, lane = threadIdx.x & 63;
    size_t row = (size_t)blockIdx.x * 4 + wid;
    float4 x = ((const float4*)&X[row * DM_])[lane];
    float4 r = ((const float4*)&Rr[row * DM_])[lane];
    float v[4] = {x.x + r.x, x.y + r.y, x.z + r.z, x.w + r.w};
    float sm = v[0] + v[1] + v[2] + v[3];
#pragma unroll
    for (int o = 32; o; o >>= 1) sm += __shfl_xor(sm, o, 64);
    float mu = sm * (1.f / 256.f);
    float q = 0.f;
#pragma unroll
    for (int i = 0; i < 4; ++i) { float d = v[i] - mu; q += d * d; }
#pragma unroll
    for (int o = 32; o; o >>= 1) q += __shfl_xor(q, o, 64);
    float inv = rsqrtf(q * (1.f / 256.f) + 1e-5f);
    int c0 = lane * 4;
    float4 gv = *(const float4*)&g[c0];
    float4 bv = *(const float4*)&bb[c0];
    float4 o4;
    o4.x = (v[0] - mu) * inv * gv.x + bv.x;
    o4.y = (v[1] - mu) * inv * gv.y + bv.y;
    o4.z = (v[2] - mu) * inv * gv.z + bv.z;
    o4.w = (v[3] - mu) * inv * gv.w + bv.w;
    ((float4*)&O[row * DM_])[lane] = o4;
    ushort4 ob;
    ob.x = f2bf(o4.x); ob.y = f2bf(o4.y); ob.z = f2bf(o4.z); ob.w = f2bf(o4.w);
    ((ushort4*)&Obf[row * DM_])[lane] = ob;
}

extern "C" void kernel_launch(void* const* d_in, const int* in_sizes, int n_in,
                              void* d_out, int out_size, void* d_ws, size_t ws_size,
                              hipStream_t stream) {
    const float* src_in[4] = {(const float*)d_in[0], (const float*)d_in[2],
                              (const float*)d_in[4], (const float*)d_in[6]};
    const float* pos_in[4] = {(const float*)d_in[1], (const float*)d_in[3],
                              (const float*)d_in[5], (const float*)d_in[7]};
    const float* lemb  = (const float*)d_in[8];
    const float* W_off = (const float*)d_in[9];
    const float* bOff  = (const float*)d_in[10];
    const float* W_att = (const float*)d_in[11];
    const float* bAtt  = (const float*)d_in[12];
    const float* W_val = (const float*)d_in[13];
    const float* bVal  = (const float*)d_in[14];
    const float* W_out = (const float*)d_in[15];
    const float* bOut  = (const float*)d_in[16];
    const float* ln1g  = (const float*)d_in[17];
    const float* ln1b  = (const float*)d_in[18];
    const float* W_ff1 = (const float*)d_in[19];
    const float* bFf1  = (const float*)d_in[20];
    const float* W_ff2 = (const float*)d_in[21];
    const float* bFf2  = (const float*)d_in[22];
    const float* ln2g  = (const float*)d_in[23];
    const float* ln2b  = (const float*)d_in[24];

    // ---- workspace layout ----
    float* ws = (float*)d_ws;
    float* b_src = ws;                                        // NQP*256 f32
    float* b_pos = b_src + (size_t)NQP_ * 256;                // NQP*256 f32
    unsigned short* b_srcbf = (unsigned short*)(b_pos + (size_t)NQP_ * 256); // NQP*256
    unsigned short* b_qbf   = b_srcbf + (size_t)NQP_ * 256;   // NQP*256
    unsigned short* b_wt    = b_qbf + (size_t)NQP_ * 256;     // 2*786432
    float* R = (float*)(b_wt + 2 * 786432);
    float* b_valb = R;                                        // NQP*256 f32
    float* b_offb = R + (size_t)NQP_ * 256;                   // NQP*384 f32
    float* b_attb = R + (size_t)NQP_ * 640;                   // NQP*128 f32
    unsigned short* b_aggbf = (unsigned short*)(R + (size_t)NQP_ * 768); // NQP*256
    float* b_tmp  = R;                                        // aliases valb
    unsigned short* b_ffhbf = (unsigned short*)R;             // NQP*1024 (aliases valb+offb)
    float* b_tmp2 = R + (size_t)NQP_ * 640;                   // aliases attb+aggbf

    // weight prep (transpose + bf16), offsets within a layer's 786432 block
    for (int l = 0; l < NL_; ++l) {
        unsigned short* wt = b_wt + (size_t)l * 786432;
        k_wprep<<<dim3(8, 8), 256, 0, stream>>>(W_val + (size_t)l * 65536, wt + 0, 256, 256);
        k_wprep<<<dim3(12, 8), 256, 0, stream>>>(W_off + (size_t)l * 98304, wt + 65536, 256, 384);
        k_wprep<<<dim3(4, 8), 256, 0, stream>>>(W_att + (size_t)l * 32768, wt + 163840, 256, 128);
        k_wprep<<<dim3(8, 8), 256, 0, stream>>>(W_out + (size_t)l * 65536, wt + 196608, 256, 256);
        k_wprep<<<dim3(32, 8), 256, 0, stream>>>(W_ff1 + (size_t)l * 262144, wt + 262144, 256, 1024);
        k_wprep<<<dim3(8, 32), 256, 0, stream>>>(W_ff2 + (size_t)l * 262144, wt + 524288, 1024, 256);
    }

    const int S[4]   = {16384, 2048, 256, 32};
    const int OFF[4] = {0, 16384, 18432, 18688};
    for (int l = 0; l < 4; ++l)
        k_flatten<<<dim3(B_ * S[l]), 256, 0, stream>>>(
            src_in[l], pos_in[l], lemb, l, S[l], OFF[l], b_src, b_srcbf, b_pos);

    const int GR = NQP_ / 128;  // 293 row tiles
    for (int l = 0; l < NL_; ++l) {
        unsigned short* wt = b_wt + (size_t)l * 786432;
        k_addq<<<dim3(2048), 256, 0, stream>>>((const float4*)b_src, (const float4*)b_pos,
                                               (ushort4*)b_qbf, NQ_ * 64);
        k_gemm<<<dim3(GR, 2), 256, 0, stream>>>(b_srcbf, wt + 0, bVal + l * 256,
                                                b_valb, nullptr, 256, 256, 0);
        k_gemm<<<dim3(GR, 3), 256, 0, stream>>>(b_qbf, wt + 65536, bOff + l * 384,
                                                b_offb, nullptr, 256, 384, 0);
        k_gemm<<<dim3(GR, 1), 256, 0, stream>>>(b_qbf, wt + 163840, bAtt + l * 128,
                                                b_attb, nullptr, 256, 128, 0);
        k_sample<<<dim3(NQ_), 256, 0, stream>>>(b_offb, b_attb, b_valb, b_aggbf);
        k_gemm<<<dim3(GR, 2), 256, 0, stream>>>(b_aggbf, wt + 196608, bOut + l * 256,
                                                b_tmp, nullptr, 256, 256, 0);
        k_add_ln<<<dim3(NQ_ / 4), 256, 0, stream>>>(b_src, b_tmp, ln1g + l * 256,
                                                    ln1b + l * 256, b_src, b_srcbf);
        k_gemm<<<dim3(GR, 8), 256, 0, stream>>>(b_srcbf, wt + 262144, bFf1 + l * 1024,
                                                nullptr, b_ffhbf, 256, 1024, 1);
        k_gemm<<<dim3(GR, 2), 256, 0, stream>>>(b_ffhbf, wt + 524288, bFf2 + l * 256,
                                                b_tmp2, nullptr, 1024, 256, 0);
        float* dst = (l == NL_ - 1) ? (float*)d_out : b_src;
        k_add_ln<<<dim3(NQ_ / 4), 256, 0, stream>>>(b_src, b_tmp2, ln2g + l * 256,
                                                    ln2b + l * 256, dst, b_srcbf);
    }
}

// Round 7
// 827.423 us; speedup vs baseline: 3.0498x; 1.1612x over previous
//
#include <hip/hip_runtime.h>
#include <hip/hip_bf16.h>
#include <math.h>

typedef __attribute__((ext_vector_type(4))) float f32x4;
typedef __attribute__((ext_vector_type(8))) short bf16x8;

static constexpr int B_   = 2;
static constexpr int DM_  = 256;
static constexpr int NL_  = 2;
static constexpr int LEN_ = 18720;
static constexpr int NQ_  = 37440;           // B*LEN
static constexpr int NQP_ = 37504;           // 128*293

__device__ __forceinline__ unsigned short f2bf(float x) {
    __hip_bfloat16 h = __float2bfloat16(x);
    return *reinterpret_cast<unsigned short*>(&h);
}

// ============ flatten: all levels in one kernel; emits src f32/bf16, pos, qbf ===
struct FlatArgs { const float* s[4]; const float* p[4]; };
__global__ __launch_bounds__(256) void k_flatten(FlatArgs a, const float* __restrict__ lemb,
                                                 float* __restrict__ src,
                                                 unsigned short* __restrict__ srcbf,
                                                 float* __restrict__ pos,
                                                 unsigned short* __restrict__ qbf) {
    int t = blockIdx.x, c = threadIdx.x;
    int l, rel;
    if (t < 32768)      { l = 0; rel = t; }
    else if (t < 36864) { l = 1; rel = t - 32768; }
    else if (t < 37376) { l = 2; rel = t - 36864; }
    else                { l = 3; rel = t - 37376; }
    const int SH[4] = {14, 11, 8, 5};            // log2(S)
    const int OFF[4] = {0, 16384, 18432, 18688};
    int S = 1 << SH[l];
    int b = rel >> SH[l], s = rel & (S - 1);
    float sv = a.s[l][(size_t)(b * DM_ + c) * S + s];
    float pv = a.p[l][(size_t)(b * DM_ + c) * S + s] + lemb[l * DM_ + c];
    size_t row = (size_t)b * LEN_ + OFF[l] + s;
    src[row * DM_ + c] = sv;
    srcbf[row * DM_ + c] = f2bf(sv);
    pos[row * DM_ + c] = pv;
    qbf[row * DM_ + c] = f2bf(sv + pv);
}

// ============ weight prep: all transposes in one kernel ============
struct WPEnt { const float* s; unsigned short* d; int K, N, start; };
struct WPArgs { WPEnt e[12]; };
__global__ __launch_bounds__(256) void k_wprep_all(WPArgs a) {
    __shared__ float t[32][33];
    int bidx = blockIdx.x;
    int i = 0;
#pragma unroll
    for (int j = 1; j < 12; ++j) if (bidx >= a.e[j].start) i = j;
    const float* W = a.e[i].s;
    unsigned short* Wt = a.e[i].d;
    int K = a.e[i].K, N = a.e[i].N;
    int ti = bidx - a.e[i].start;
    int tilesX = N >> 5;
    int bx = ti % tilesX, by = ti / tilesX;
    int n0 = bx * 32, k0 = by * 32;
    int tx = threadIdx.x & 31, ty = threadIdx.x >> 5;
#pragma unroll
    for (int q = 0; q < 4; ++q)
        t[ty + q * 8][tx] = W[(size_t)(k0 + ty + q * 8) * N + n0 + tx];
    __syncthreads();
#pragma unroll
    for (int q = 0; q < 4; ++q)
        Wt[(size_t)(n0 + ty + q * 8) * K + k0 + tx] = f2bf(t[tx][ty + q * 8]);
}

// ============ bf16 MFMA GEMM, 128x128 tile, BK=32 ============
// MODE 0: C fp32.  MODE 1: relu -> Cbf bf16.  MODE 2: Cbf bf16.
template<int K, int MODE>
__global__ __launch_bounds__(256) void k_gemm(const unsigned short* __restrict__ A,
                                              const unsigned short* __restrict__ Bt,
                                              const float* __restrict__ bias,
                                              const float* __restrict__ bias2,
                                              int nsplit,
                                              float* __restrict__ C,
                                              unsigned short* __restrict__ Cbf,
                                              int N) {
    __shared__ unsigned short As[128 * 32];
    __shared__ unsigned short Bs[128 * 32];
    int tid = threadIdx.x;
    int w = tid >> 6, lane = tid & 63;
    int wr = w >> 1, wc = w & 1;
    int row0 = blockIdx.x * 128, col0 = blockIdx.y * 128;

    const unsigned short* gA = A + (size_t)(row0 + w * 32 + (lane >> 2)) * K + (lane & 3) * 8;
    const unsigned short* gB = Bt + (size_t)(col0 + w * 32 + (lane >> 2)) * K + (lane & 3) * 8;
    char* lA0 = (char*)As + w * 2048;
    char* lB0 = (char*)Bs + w * 2048;

    f32x4 acc[4][4];
#pragma unroll
    for (int m = 0; m < 4; ++m)
#pragma unroll
        for (int n = 0; n < 4; ++n) acc[m][n] = (f32x4){0.f, 0.f, 0.f, 0.f};

    int lr = lane & 15, lk = (lane >> 4) * 8;
    const unsigned short* pA = &As[(wr * 64 + lr) * 32 + lk];
    const unsigned short* pB = &Bs[(wc * 64 + lr) * 32 + lk];

    for (int kt = 0; kt < K; kt += 32) {
        __builtin_amdgcn_global_load_lds((const __attribute__((address_space(1))) void*)gA,
                                         (__attribute__((address_space(3))) void*)lA0, 16, 0, 0);
        __builtin_amdgcn_global_load_lds((const __attribute__((address_space(1))) void*)(gA + (size_t)16 * K),
                                         (__attribute__((address_space(3))) void*)(lA0 + 1024), 16, 0, 0);
        __builtin_amdgcn_global_load_lds((const __attribute__((address_space(1))) void*)gB,
                                         (__attribute__((address_space(3))) void*)lB0, 16, 0, 0);
        __builtin_amdgcn_global_load_lds((const __attribute__((address_space(1))) void*)(gB + (size_t)16 * K),
                                         (__attribute__((address_space(3))) void*)(lB0 + 1024), 16, 0, 0);
        gA += 32; gB += 32;
        __syncthreads();
        bf16x8 a[4], b[4];
#pragma unroll
        for (int m = 0; m < 4; ++m) a[m] = *(const bf16x8*)(pA + m * 16 * 32);
#pragma unroll
        for (int n = 0; n < 4; ++n) b[n] = *(const bf16x8*)(pB + n * 16 * 32);
#pragma unroll
        for (int m = 0; m < 4; ++m)
#pragma unroll
            for (int n = 0; n < 4; ++n)
                acc[m][n] = __builtin_amdgcn_mfma_f32_16x16x32_bf16(a[m], b[n], acc[m][n], 0, 0, 0);
        __syncthreads();
    }

    int fr = (lane >> 4) * 4, fc = lane & 15;
#pragma unroll
    for (int m = 0; m < 4; ++m) {
#pragma unroll
        for (int n = 0; n < 4; ++n) {
            int cc = col0 + wc * 64 + n * 16 + fc;
            float bv = (cc < nsplit) ? bias[cc] : bias2[cc - nsplit];
#pragma unroll
            for (int i = 0; i < 4; ++i) {
                int cr = row0 + wr * 64 + m * 16 + fr + i;
                float v = acc[m][n][i] + bv;
                if (MODE == 1) {
                    Cbf[(size_t)cr * N + cc] = f2bf(fmaxf(v, 0.f));
                } else if (MODE == 2) {
                    Cbf[(size_t)cr * N + cc] = f2bf(v);
                } else {
                    C[(size_t)cr * N + cc] = v;
                }
            }
        }
    }
}

// ============ fused softmax + trilinear sampling ============
// oa: [row][512] fp32 (0..383 offsets, 384..511 logits); value bf16.
__global__ __launch_bounds__(256) void k_sample(const float* __restrict__ oa,
                                                const unsigned short* __restrict__ vbf,
                                                unsigned short* __restrict__ aggbf) {
    int bid = blockIdx.x;
    int row = (bid & 7) * (NQ_ / 8) + (bid >> 3);   // XCD-chunked swizzle
    int b = row / LEN_, qi = row - b * LEN_;
    __shared__ float sw[8][128];
    __shared__ int sidx[8][128];
    int tid = threadIdx.x;

    int lq, s;
    if (qi < 16384)      { lq = 0; s = qi; }
    else if (qi < 18432) { lq = 1; s = qi - 16384; }
    else if (qi < 18688) { lq = 2; s = qi - 18432; }
    else                 { lq = 3; s = qi - 18688; }
    const int dD[4] = {16, 8, 4, 2}, dH[4] = {32, 16, 8, 4}, dW[4] = {32, 16, 8, 4};
    const int loff[4] = {0, 16384, 18432, 18688};
    int Dq = dD[lq], Hq = dH[lq], Wq = dW[lq];
    int zq = s / (Hq * Wq);
    int rr = s - zq * (Hq * Wq);
    int yq = rr / Wq, xq = rr - (rr / Wq) * Wq;
    float ref0 = (zq + 0.5f) / Dq, ref1 = (yq + 0.5f) / Hq, ref2 = (xq + 0.5f) / Wq;

    if (tid < 128) {
        int m = tid >> 4, l = (tid >> 2) & 3;
        float e = oa[(size_t)row * 512 + 384 + tid];
        float mx = e;
#pragma unroll
        for (int o = 1; o < 16; o <<= 1) mx = fmaxf(mx, __shfl_xor(mx, o, 16));
        float ex = expf(e - mx);
        float sm = ex;
#pragma unroll
        for (int o = 1; o < 16; o <<= 1) sm += __shfl_xor(sm, o, 16);
        float aw = ex / sm;

        const int D_ = dD[l], H_ = dH[l], W_ = dW[l];
        float o0 = oa[(size_t)row * 512 + tid * 3 + 0];
        float o1 = oa[(size_t)row * 512 + tid * 3 + 1];
        float o2 = oa[(size_t)row * 512 + tid * 3 + 2];
        float x = (ref0 + o0 / W_) * W_ - 0.5f;
        float y = (ref1 + o1 / H_) * H_ - 0.5f;
        float z = (ref2 + o2 / D_) * D_ - 0.5f;
        float xf = floorf(x), yf = floorf(y), zf = floorf(z);
        float fx = x - xf, fy = y - yf, fz = z - zf;
        int x0 = (int)xf, y0 = (int)yf, z0 = (int)zf;
        int vbase = (b * LEN_ + loff[l]) * DM_ + m * 32;
#pragma unroll
        for (int dz = 0; dz < 2; ++dz)
#pragma unroll
            for (int dy = 0; dy < 2; ++dy)
#pragma unroll
                for (int dx = 0; dx < 2; ++dx) {
                    int xi = x0 + dx, yi = y0 + dy, zi = z0 + dz;
                    float wgt = (dx ? fx : 1.f - fx) * (dy ? fy : 1.f - fy) * (dz ? fz : 1.f - fz);
                    bool valid = (xi >= 0) & (xi < W_) & (yi >= 0) & (yi < H_) &
                                 (zi >= 0) & (zi < D_);
                    int xc = min(max(xi, 0), W_ - 1);
                    int yc = min(max(yi, 0), H_ - 1);
                    int zc = min(max(zi, 0), D_ - 1);
                    int idx = (zc * H_ + yc) * W_ + xc;
                    int cr = (dz << 2) | (dy << 1) | dx;
                    sw[cr][tid] = valid ? aw * wgt : 0.f;
                    sidx[cr][tid] = vbase + idx * DM_;
                }
    }
    __syncthreads();

    int m = tid >> 5, h = (tid >> 4) & 1, cp = tid & 15;
    float acc0 = 0.f, acc1 = 0.f;
#pragma unroll
    for (int t8 = 0; t8 < 8; ++t8) {
        int tq = m * 16 + h * 8 + t8;
#pragma unroll
        for (int cr = 0; cr < 8; ++cr) {
            float wq = sw[cr][tq];
            int ofs = sidx[cr][tq];
            unsigned int v = *(const unsigned int*)&vbf[ofs + cp * 2];
            float f0 = __uint_as_float(v << 16);
            float f1 = __uint_as_float(v & 0xffff0000u);
            acc0 = fmaf(wq, f0, acc0);
            acc1 = fmaf(wq, f1, acc1);
        }
    }
    acc0 += __shfl_xor(acc0, 16, 64);
    acc1 += __shfl_xor(acc1, 16, 64);
    if (h == 0) {
        ushort2 o;
        o.x = f2bf(acc0);
        o.y = f2bf(acc1);
        *(ushort2*)&aggbf[(size_t)row * DM_ + m * 32 + cp * 2] = o;
    }
}

// ============ fused residual-add + LayerNorm (+opt bf16 out, +opt qbf) ========
__global__ __launch_bounds__(256) void k_add_ln(const float* __restrict__ X,
                                                const float* __restrict__ Rr,
                                                const float* __restrict__ g,
                                                const float* __restrict__ bb,
                                                float* __restrict__ O,
                                                unsigned short* __restrict__ Obf,
                                                const float* __restrict__ pos,
                                                unsigned short* __restrict__ qbf) {
    int wid = threadIdx.x >> 6, lane = threadIdx.x & 63;
    size_t row = (size_t)blockIdx.x * 4 + wid;
    float4 x = ((const float4*)&X[row * DM_])[lane];
    float4 r = ((const float4*)&Rr[row * DM_])[lane];
    float v[4] = {x.x + r.x, x.y + r.y, x.z + r.z, x.w + r.w};
    float sm = v[0] + v[1] + v[2] + v[3];
#pragma unroll
    for (int o = 32; o; o >>= 1) sm += __shfl_xor(sm, o, 64);
    float mu = sm * (1.f / 256.f);
    float q = 0.f;
#pragma unroll
    for (int i = 0; i < 4; ++i) { float d = v[i] - mu; q += d * d; }
#pragma unroll
    for (int o = 32; o; o >>= 1) q += __shfl_xor(q, o, 64);
    float inv = rsqrtf(q * (1.f / 256.f) + 1e-5f);
    int c0 = lane * 4;
    float4 gv = *(const float4*)&g[c0];
    float4 bv = *(const float4*)&bb[c0];
    float4 o4;
    o4.x = (v[0] - mu) * inv * gv.x + bv.x;
    o4.y = (v[1] - mu) * inv * gv.y + bv.y;
    o4.z = (v[2] - mu) * inv * gv.z + bv.z;
    o4.w = (v[3] - mu) * inv * gv.w + bv.w;
    ((float4*)&O[row * DM_])[lane] = o4;
    if (Obf) {
        ushort4 ob;
        ob.x = f2bf(o4.x); ob.y = f2bf(o4.y); ob.z = f2bf(o4.z); ob.w = f2bf(o4.w);
        ((ushort4*)&Obf[row * DM_])[lane] = ob;
    }
    if (qbf) {
        float4 pv = ((const float4*)&pos[row * DM_])[lane];
        ushort4 qb;
        qb.x = f2bf(o4.x + pv.x); qb.y = f2bf(o4.y + pv.y);
        qb.z = f2bf(o4.z + pv.z); qb.w = f2bf(o4.w + pv.w);
        ((ushort4*)&qbf[row * DM_])[lane] = qb;
    }
}

extern "C" void kernel_launch(void* const* d_in, const int* in_sizes, int n_in,
                              void* d_out, int out_size, void* d_ws, size_t ws_size,
                              hipStream_t stream) {
    const float* lemb  = (const float*)d_in[8];
    const float* W_off = (const float*)d_in[9];
    const float* bOff  = (const float*)d_in[10];
    const float* W_att = (const float*)d_in[11];
    const float* bAtt  = (const float*)d_in[12];
    const float* W_val = (const float*)d_in[13];
    const float* bVal  = (const float*)d_in[14];
    const float* W_out = (const float*)d_in[15];
    const float* bOut  = (const float*)d_in[16];
    const float* ln1g  = (const float*)d_in[17];
    const float* ln1b  = (const float*)d_in[18];
    const float* W_ff1 = (const float*)d_in[19];
    const float* bFf1  = (const float*)d_in[20];
    const float* W_ff2 = (const float*)d_in[21];
    const float* bFf2  = (const float*)d_in[22];
    const float* ln2g  = (const float*)d_in[23];
    const float* ln2b  = (const float*)d_in[24];

    // ---- workspace layout (byte offsets) ----
    char* ws = (char*)d_ws;
    const size_t NR = (size_t)NQP_ * 256;
    float* b_src = (float*)ws;                                   // NR f32
    float* b_pos = (float*)(ws + NR * 4);                        // NR f32
    unsigned short* b_srcbf = (unsigned short*)(ws + NR * 8);    // NR bf16
    unsigned short* b_qbf   = (unsigned short*)(ws + NR * 10);   // NR bf16
    unsigned short* b_wt    = (unsigned short*)(ws + NR * 12);   // 2*786432 bf16
    char* R = ws + NR * 12 + (size_t)2 * 786432 * 2;
    unsigned short* b_valbf = (unsigned short*)(R);              // NR bf16
    float* b_oa             = (float*)(R + NR * 2);              // NQP*512 f32
    unsigned short* b_aggbf = (unsigned short*)(R + NR * 10);    // NR bf16
    float* b_tmp            = (float*)(R);                       // NR f32 (overlays valbf/oa)
    unsigned short* b_ffhbf = (unsigned short*)(R + NR * 4);     // NQP*1024 bf16
    float* b_tmp2           = (float*)(R);                       // NR f32

    // ---- weight prep: one kernel, 12 transposes ----
    WPArgs wa;
    int start = 0;
    for (int l = 0; l < NL_; ++l) {
        unsigned short* wt = b_wt + (size_t)l * 786432;
        WPEnt ents[6] = {
            {W_val + (size_t)l * 65536,  wt + 0,      256, 256,  start},
            {W_off + (size_t)l * 98304,  wt + 65536,  256, 384,  start + 64},
            {W_att + (size_t)l * 32768,  wt + 163840, 256, 128,  start + 160},
            {W_out + (size_t)l * 65536,  wt + 196608, 256, 256,  start + 192},
            {W_ff1 + (size_t)l * 262144, wt + 262144, 256, 1024, start + 256},
            {W_ff2 + (size_t)l * 262144, wt + 524288, 1024, 256, start + 512},
        };
        for (int j = 0; j < 6; ++j) wa.e[l * 6 + j] = ents[j];
        start += 768;
    }
    k_wprep_all<<<dim3(1536), 256, 0, stream>>>(wa);

    FlatArgs fa;
    for (int i = 0; i < 4; ++i) {
        fa.s[i] = (const float*)d_in[2 * i];
        fa.p[i] = (const float*)d_in[2 * i + 1];
    }
    k_flatten<<<dim3(NQ_), 256, 0, stream>>>(fa, lemb, b_src, b_srcbf, b_pos, b_qbf);

    const int GR = NQP_ / 128;  // 293
    const int BIG = 1 << 30;
    for (int l = 0; l < NL_; ++l) {
        unsigned short* wt = b_wt + (size_t)l * 786432;
        k_gemm<256, 2><<<dim3(GR, 2), 256, 0, stream>>>(
            b_srcbf, wt + 0, bVal + l * 256, bVal + l * 256, BIG, nullptr, b_valbf, 256);
        k_gemm<256, 0><<<dim3(GR, 4), 256, 0, stream>>>(
            b_qbf, wt + 65536, bOff + l * 384, bAtt + l * 128, 384, b_oa, nullptr, 512);
        k_sample<<<dim3(NQ_), 256, 0, stream>>>(b_oa, b_valbf, b_aggbf);
        k_gemm<256, 0><<<dim3(GR, 2), 256, 0, stream>>>(
            b_aggbf, wt + 196608, bOut + l * 256, bOut + l * 256, BIG, b_tmp, nullptr, 256);
        k_add_ln<<<dim3(NQ_ / 4), 256, 0, stream>>>(b_src, b_tmp, ln1g + l * 256,
                                                    ln1b + l * 256, b_src, b_srcbf,
                                                    nullptr, nullptr);
        k_gemm<256, 1><<<dim3(GR, 8), 256, 0, stream>>>(
            b_srcbf, wt + 262144, bFf1 + l * 1024, bFf1 + l * 1024, BIG, nullptr, b_ffhbf, 1024);
        k_gemm<1024, 0><<<dim3(GR, 2), 256, 0, stream>>>(
            b_ffhbf, wt + 524288, bFf2 + l * 256, bFf2 + l * 256, BIG, b_tmp2, nullptr, 256);
        float* dst = (l == NL_ - 1) ? (float*)d_out : b_src;
        int last = (l == NL_ - 1);
        k_add_ln<<<dim3(NQ_ / 4), 256, 0, stream>>>(b_src, b_tmp2, ln2g + l * 256,
                                                    ln2b + l * 256, dst,
                                                    last ? nullptr : b_srcbf,
                                                    last ? nullptr : b_pos,
                                                    last ? nullptr : b_qbf);
    }
}

// Round 8
// 813.618 us; speedup vs baseline: 3.1016x; 1.0170x over previous
//
#include <hip/hip_runtime.h>
#include <hip/hip_bf16.h>
#include <math.h>

typedef __attribute__((ext_vector_type(4))) float f32x4;
typedef __attribute__((ext_vector_type(8))) short bf16x8;

static constexpr int B_   = 2;
static constexpr int DM_  = 256;
static constexpr int NL_  = 2;
static constexpr int LEN_ = 18720;
static constexpr int NQ_  = 37440;           // B*LEN
static constexpr int NQP_ = 37504;           // 128*293

__device__ __forceinline__ unsigned short f2bf(float x) {
    __hip_bfloat16 h = __float2bfloat16(x);
    return *reinterpret_cast<unsigned short*>(&h);
}

// ============ flatten: all levels in one kernel; emits src f32/bf16, pos, qbf ===
struct FlatArgs { const float* s[4]; const float* p[4]; };
__global__ __launch_bounds__(256) void k_flatten(FlatArgs a, const float* __restrict__ lemb,
                                                 float* __restrict__ src,
                                                 unsigned short* __restrict__ srcbf,
                                                 float* __restrict__ pos,
                                                 unsigned short* __restrict__ qbf) {
    int t = blockIdx.x, c = threadIdx.x;
    int l, rel;
    if (t < 32768)      { l = 0; rel = t; }
    else if (t < 36864) { l = 1; rel = t - 32768; }
    else if (t < 37376) { l = 2; rel = t - 36864; }
    else                { l = 3; rel = t - 37376; }
    const int SH[4] = {14, 11, 8, 5};            // log2(S)
    const int OFF[4] = {0, 16384, 18432, 18688};
    int S = 1 << SH[l];
    int b = rel >> SH[l], s = rel & (S - 1);
    float sv = a.s[l][(size_t)(b * DM_ + c) * S + s];
    float pv = a.p[l][(size_t)(b * DM_ + c) * S + s] + lemb[l * DM_ + c];
    size_t row = (size_t)b * LEN_ + OFF[l] + s;
    src[row * DM_ + c] = sv;
    srcbf[row * DM_ + c] = f2bf(sv);
    pos[row * DM_ + c] = pv;
    qbf[row * DM_ + c] = f2bf(sv + pv);
}

// ============ weight prep: all transposes in one kernel ============
struct WPEnt { const float* s; unsigned short* d; int K, N, start; };
struct WPArgs { WPEnt e[12]; };
__global__ __launch_bounds__(256) void k_wprep_all(WPArgs a) {
    __shared__ float t[32][33];
    int bidx = blockIdx.x;
    int i = 0;
#pragma unroll
    for (int j = 1; j < 12; ++j) if (bidx >= a.e[j].start) i = j;
    const float* W = a.e[i].s;
    unsigned short* Wt = a.e[i].d;
    int K = a.e[i].K, N = a.e[i].N;
    int ti = bidx - a.e[i].start;
    int tilesX = N >> 5;
    int bx = ti % tilesX, by = ti / tilesX;
    int n0 = bx * 32, k0 = by * 32;
    int tx = threadIdx.x & 31, ty = threadIdx.x >> 5;
#pragma unroll
    for (int q = 0; q < 4; ++q)
        t[ty + q * 8][tx] = W[(size_t)(k0 + ty + q * 8) * N + n0 + tx];
    __syncthreads();
#pragma unroll
    for (int q = 0; q < 4; ++q)
        Wt[(size_t)(n0 + ty + q * 8) * K + k0 + tx] = f2bf(t[tx][ty + q * 8]);
}

// ============ bf16 MFMA GEMM, 128x128 tile, BK=32 ============
// MODE 0: C fp32.  MODE 1: relu -> Cbf bf16.  MODE 2: Cbf bf16.
template<int K, int MODE>
__global__ __launch_bounds__(256) void k_gemm(const unsigned short* __restrict__ A,
                                              const unsigned short* __restrict__ Bt,
                                              const float* __restrict__ bias,
                                              const float* __restrict__ bias2,
                                              int nsplit,
                                              float* __restrict__ C,
                                              unsigned short* __restrict__ Cbf,
                                              int N) {
    __shared__ unsigned short As[128 * 32];
    __shared__ unsigned short Bs[128 * 32];
    int tid = threadIdx.x;
    int w = tid >> 6, lane = tid & 63;
    int wr = w >> 1, wc = w & 1;
    int row0 = blockIdx.x * 128, col0 = blockIdx.y * 128;

    const unsigned short* gA = A + (size_t)(row0 + w * 32 + (lane >> 2)) * K + (lane & 3) * 8;
    const unsigned short* gB = Bt + (size_t)(col0 + w * 32 + (lane >> 2)) * K + (lane & 3) * 8;
    char* lA0 = (char*)As + w * 2048;
    char* lB0 = (char*)Bs + w * 2048;

    f32x4 acc[4][4];
#pragma unroll
    for (int m = 0; m < 4; ++m)
#pragma unroll
        for (int n = 0; n < 4; ++n) acc[m][n] = (f32x4){0.f, 0.f, 0.f, 0.f};

    int lr = lane & 15, lk = (lane >> 4) * 8;
    const unsigned short* pA = &As[(wr * 64 + lr) * 32 + lk];
    const unsigned short* pB = &Bs[(wc * 64 + lr) * 32 + lk];

    for (int kt = 0; kt < K; kt += 32) {
        __builtin_amdgcn_global_load_lds((const __attribute__((address_space(1))) void*)gA,
                                         (__attribute__((address_space(3))) void*)lA0, 16, 0, 0);
        __builtin_amdgcn_global_load_lds((const __attribute__((address_space(1))) void*)(gA + (size_t)16 * K),
                                         (__attribute__((address_space(3))) void*)(lA0 + 1024), 16, 0, 0);
        __builtin_amdgcn_global_load_lds((const __attribute__((address_space(1))) void*)gB,
                                         (__attribute__((address_space(3))) void*)lB0, 16, 0, 0);
        __builtin_amdgcn_global_load_lds((const __attribute__((address_space(1))) void*)(gB + (size_t)16 * K),
                                         (__attribute__((address_space(3))) void*)(lB0 + 1024), 16, 0, 0);
        gA += 32; gB += 32;
        __syncthreads();
        bf16x8 a[4], b[4];
#pragma unroll
        for (int m = 0; m < 4; ++m) a[m] = *(const bf16x8*)(pA + m * 16 * 32);
#pragma unroll
        for (int n = 0; n < 4; ++n) b[n] = *(const bf16x8*)(pB + n * 16 * 32);
#pragma unroll
        for (int m = 0; m < 4; ++m)
#pragma unroll
            for (int n = 0; n < 4; ++n)
                acc[m][n] = __builtin_amdgcn_mfma_f32_16x16x32_bf16(a[m], b[n], acc[m][n], 0, 0, 0);
        __syncthreads();
    }

    int fr = (lane >> 4) * 4, fc = lane & 15;
#pragma unroll
    for (int m = 0; m < 4; ++m) {
#pragma unroll
        for (int n = 0; n < 4; ++n) {
            int cc = col0 + wc * 64 + n * 16 + fc;
            float bv = (cc < nsplit) ? bias[cc] : bias2[cc - nsplit];
#pragma unroll
            for (int i = 0; i < 4; ++i) {
                int cr = row0 + wr * 64 + m * 16 + fr + i;
                float v = acc[m][n][i] + bv;
                if (MODE == 1) {
                    Cbf[(size_t)cr * N + cc] = f2bf(fmaxf(v, 0.f));
                } else if (MODE == 2) {
                    Cbf[(size_t)cr * N + cc] = f2bf(v);
                } else {
                    C[(size_t)cr * N + cc] = v;
                }
            }
        }
    }
}

// ============ fused softmax + trilinear sampling (v3: dwordx4 gathers) =======
// oa: [row][512] fp32 (0..383 offsets, 384..511 logits); value bf16.
__global__ __launch_bounds__(256) void k_sample(const float* __restrict__ oa,
                                                const unsigned short* __restrict__ vbf,
                                                unsigned short* __restrict__ aggbf) {
    int bid = blockIdx.x;
    int row = (bid & 7) * (NQ_ / 8) + (bid >> 3);   // XCD-chunked swizzle
    int b = row / LEN_, qi = row - b * LEN_;
    __shared__ float sw[8][128];
    __shared__ int sidx[8][128];
    int tid = threadIdx.x;

    int lq, s;
    if (qi < 16384)      { lq = 0; s = qi; }
    else if (qi < 18432) { lq = 1; s = qi - 16384; }
    else if (qi < 18688) { lq = 2; s = qi - 18432; }
    else                 { lq = 3; s = qi - 18688; }
    const int dD[4] = {16, 8, 4, 2}, dH[4] = {32, 16, 8, 4}, dW[4] = {32, 16, 8, 4};
    const int loff[4] = {0, 16384, 18432, 18688};
    int Dq = dD[lq], Hq = dH[lq], Wq = dW[lq];
    int zq = s / (Hq * Wq);
    int rr = s - zq * (Hq * Wq);
    int yq = rr / Wq, xq = rr - (rr / Wq) * Wq;
    float ref0 = (zq + 0.5f) / Dq, ref1 = (yq + 0.5f) / Hq, ref2 = (xq + 0.5f) / Wq;

    if (tid < 128) {
        int m = tid >> 4, l = (tid >> 2) & 3;
        float e = oa[(size_t)row * 512 + 384 + tid];
        float mx = e;
#pragma unroll
        for (int o = 1; o < 16; o <<= 1) mx = fmaxf(mx, __shfl_xor(mx, o, 16));
        float ex = expf(e - mx);
        float sm = ex;
#pragma unroll
        for (int o = 1; o < 16; o <<= 1) sm += __shfl_xor(sm, o, 16);
        float aw = ex / sm;

        const int D_ = dD[l], H_ = dH[l], W_ = dW[l];
        float o0 = oa[(size_t)row * 512 + tid * 3 + 0];
        float o1 = oa[(size_t)row * 512 + tid * 3 + 1];
        float o2 = oa[(size_t)row * 512 + tid * 3 + 2];
        float x = (ref0 + o0 / W_) * W_ - 0.5f;
        float y = (ref1 + o1 / H_) * H_ - 0.5f;
        float z = (ref2 + o2 / D_) * D_ - 0.5f;
        float xf = floorf(x), yf = floorf(y), zf = floorf(z);
        float fx = x - xf, fy = y - yf, fz = z - zf;
        int x0 = (int)xf, y0 = (int)yf, z0 = (int)zf;
        int vbase = (b * LEN_ + loff[l]) * DM_ + m * 32;
#pragma unroll
        for (int dz = 0; dz < 2; ++dz)
#pragma unroll
            for (int dy = 0; dy < 2; ++dy)
#pragma unroll
                for (int dx = 0; dx < 2; ++dx) {
                    int xi = x0 + dx, yi = y0 + dy, zi = z0 + dz;
                    float wgt = (dx ? fx : 1.f - fx) * (dy ? fy : 1.f - fy) * (dz ? fz : 1.f - fz);
                    bool valid = (xi >= 0) & (xi < W_) & (yi >= 0) & (yi < H_) &
                                 (zi >= 0) & (zi < D_);
                    int xc = min(max(xi, 0), W_ - 1);
                    int yc = min(max(yi, 0), H_ - 1);
                    int zc = min(max(zi, 0), D_ - 1);
                    int idx = (zc * H_ + yc) * W_ + xc;
                    int cr = (dz << 2) | (dy << 1) | dx;
                    sw[cr][tid] = valid ? aw * wgt : 0.f;
                    sidx[cr][tid] = vbase + idx * DM_;
                }
    }
    __syncthreads();

    // phase 2: 32 lanes per head m = 8 pair-subsets x 4 channel-groups(8ch)
    int m = tid >> 5;
    int lane5 = tid & 31;
    int sub = lane5 >> 2, cg = lane5 & 3;
    float acc[8];
#pragma unroll
    for (int i = 0; i < 8; ++i) acc[i] = 0.f;
#pragma unroll
    for (int t = 0; t < 16; ++t) {
        int pair = sub * 16 + t;           // 128 (point,corner) pairs
        int tq = pair >> 3, cr = pair & 7;
        float wq = sw[cr][m * 16 + tq];
        int ofs = sidx[cr][m * 16 + tq];
        uint4 v = *(const uint4*)&vbf[ofs + cg * 8];
        float f0 = __uint_as_float(v.x << 16);
        float f1 = __uint_as_float(v.x & 0xffff0000u);
        float f2 = __uint_as_float(v.y << 16);
        float f3 = __uint_as_float(v.y & 0xffff0000u);
        float f4 = __uint_as_float(v.z << 16);
        float f5 = __uint_as_float(v.z & 0xffff0000u);
        float f6 = __uint_as_float(v.w << 16);
        float f7 = __uint_as_float(v.w & 0xffff0000u);
        acc[0] = fmaf(wq, f0, acc[0]);
        acc[1] = fmaf(wq, f1, acc[1]);
        acc[2] = fmaf(wq, f2, acc[2]);
        acc[3] = fmaf(wq, f3, acc[3]);
        acc[4] = fmaf(wq, f4, acc[4]);
        acc[5] = fmaf(wq, f5, acc[5]);
        acc[6] = fmaf(wq, f6, acc[6]);
        acc[7] = fmaf(wq, f7, acc[7]);
    }
#pragma unroll
    for (int i = 0; i < 8; ++i) {
        acc[i] += __shfl_xor(acc[i], 4, 64);
        acc[i] += __shfl_xor(acc[i], 8, 64);
        acc[i] += __shfl_xor(acc[i], 16, 64);
    }
    if (sub == 0) {
        uint4 o;
        o.x = ((unsigned)f2bf(acc[1]) << 16) | f2bf(acc[0]);
        o.y = ((unsigned)f2bf(acc[3]) << 16) | f2bf(acc[2]);
        o.z = ((unsigned)f2bf(acc[5]) << 16) | f2bf(acc[4]);
        o.w = ((unsigned)f2bf(acc[7]) << 16) | f2bf(acc[6]);
        *(uint4*)&aggbf[(size_t)row * DM_ + m * 32 + cg * 8] = o;
    }
}

// ============ fused residual-add + LayerNorm (+opt bf16 out, +opt qbf) ========
__global__ __launch_bounds__(256) void k_add_ln(const float* __restrict__ X,
                                                const float* __restrict__ Rr,
                                                const float* __restrict__ g,
                                                const float* __restrict__ bb,
                                                float* __restrict__ O,
                                                unsigned short* __restrict__ Obf,
                                                const float* __restrict__ pos,
                                                unsigned short* __restrict__ qbf) {
    int wid = threadIdx.x >> 6, lane = threadIdx.x & 63;
    size_t row = (size_t)blockIdx.x * 4 + wid;
    float4 x = ((const float4*)&X[row * DM_])[lane];
    float4 r = ((const float4*)&Rr[row * DM_])[lane];
    float v[4] = {x.x + r.x, x.y + r.y, x.z + r.z, x.w + r.w};
    float sm = v[0] + v[1] + v[2] + v[3];
#pragma unroll
    for (int o = 32; o; o >>= 1) sm += __shfl_xor(sm, o, 64);
    float mu = sm * (1.f / 256.f);
    float q = 0.f;
#pragma unroll
    for (int i = 0; i < 4; ++i) { float d = v[i] - mu; q += d * d; }
#pragma unroll
    for (int o = 32; o; o >>= 1) q += __shfl_xor(q, o, 64);
    float inv = rsqrtf(q * (1.f / 256.f) + 1e-5f);
    int c0 = lane * 4;
    float4 gv = *(const float4*)&g[c0];
    float4 bv = *(const float4*)&bb[c0];
    float4 o4;
    o4.x = (v[0] - mu) * inv * gv.x + bv.x;
    o4.y = (v[1] - mu) * inv * gv.y + bv.y;
    o4.z = (v[2] - mu) * inv * gv.z + bv.z;
    o4.w = (v[3] - mu) * inv * gv.w + bv.w;
    ((float4*)&O[row * DM_])[lane] = o4;
    if (Obf) {
        ushort4 ob;
        ob.x = f2bf(o4.x); ob.y = f2bf(o4.y); ob.z = f2bf(o4.z); ob.w = f2bf(o4.w);
        ((ushort4*)&Obf[row * DM_])[lane] = ob;
    }
    if (qbf) {
        float4 pv = ((const float4*)&pos[row * DM_])[lane];
        ushort4 qb;
        qb.x = f2bf(o4.x + pv.x); qb.y = f2bf(o4.y + pv.y);
        qb.z = f2bf(o4.z + pv.z); qb.w = f2bf(o4.w + pv.w);
        ((ushort4*)&qbf[row * DM_])[lane] = qb;
    }
}

extern "C" void kernel_launch(void* const* d_in, const int* in_sizes, int n_in,
                              void* d_out, int out_size, void* d_ws, size_t ws_size,
                              hipStream_t stream) {
    const float* lemb  = (const float*)d_in[8];
    const float* W_off = (const float*)d_in[9];
    const float* bOff  = (const float*)d_in[10];
    const float* W_att = (const float*)d_in[11];
    const float* bAtt  = (const float*)d_in[12];
    const float* W_val = (const float*)d_in[13];
    const float* bVal  = (const float*)d_in[14];
    const float* W_out = (const float*)d_in[15];
    const float* bOut  = (const float*)d_in[16];
    const float* ln1g  = (const float*)d_in[17];
    const float* ln1b  = (const float*)d_in[18];
    const float* W_ff1 = (const float*)d_in[19];
    const float* bFf1  = (const float*)d_in[20];
    const float* W_ff2 = (const float*)d_in[21];
    const float* bFf2  = (const float*)d_in[22];
    const float* ln2g  = (const float*)d_in[23];
    const float* ln2b  = (const float*)d_in[24];

    // ---- workspace layout (byte offsets) ----
    char* ws = (char*)d_ws;
    const size_t NR = (size_t)NQP_ * 256;
    float* b_src = (float*)ws;                                   // NR f32
    float* b_pos = (float*)(ws + NR * 4);                        // NR f32
    unsigned short* b_srcbf = (unsigned short*)(ws + NR * 8);    // NR bf16
    unsigned short* b_qbf   = (unsigned short*)(ws + NR * 10);   // NR bf16
    unsigned short* b_wt    = (unsigned short*)(ws + NR * 12);   // 2*786432 bf16
    char* R = ws + NR * 12 + (size_t)2 * 786432 * 2;
    unsigned short* b_valbf = (unsigned short*)(R);              // NR bf16
    float* b_oa             = (float*)(R + NR * 2);              // NQP*512 f32
    unsigned short* b_aggbf = (unsigned short*)(R + NR * 10);    // NR bf16
    float* b_tmp            = (float*)(R);                       // NR f32 (overlays valbf/oa)
    unsigned short* b_ffhbf = (unsigned short*)(R + NR * 4);     // NQP*1024 bf16
    float* b_tmp2           = (float*)(R);                       // NR f32

    // ---- weight prep: one kernel, 12 transposes ----
    WPArgs wa;
    int start = 0;
    for (int l = 0; l < NL_; ++l) {
        unsigned short* wt = b_wt + (size_t)l * 786432;
        WPEnt ents[6] = {
            {W_val + (size_t)l * 65536,  wt + 0,      256, 256,  start},
            {W_off + (size_t)l * 98304,  wt + 65536,  256, 384,  start + 64},
            {W_att + (size_t)l * 32768,  wt + 163840, 256, 128,  start + 160},
            {W_out + (size_t)l * 65536,  wt + 196608, 256, 256,  start + 192},
            {W_ff1 + (size_t)l * 262144, wt + 262144, 256, 1024, start + 256},
            {W_ff2 + (size_t)l * 262144, wt + 524288, 1024, 256, start + 512},
        };
        for (int j = 0; j < 6; ++j) wa.e[l * 6 + j] = ents[j];
        start += 768;
    }
    k_wprep_all<<<dim3(1536), 256, 0, stream>>>(wa);

    FlatArgs fa;
    for (int i = 0; i < 4; ++i) {
        fa.s[i] = (const float*)d_in[2 * i];
        fa.p[i] = (const float*)d_in[2 * i + 1];
    }
    k_flatten<<<dim3(NQ_), 256, 0, stream>>>(fa, lemb, b_src, b_srcbf, b_pos, b_qbf);

    const int GR = NQP_ / 128;  // 293
    const int BIG = 1 << 30;
    for (int l = 0; l < NL_; ++l) {
        unsigned short* wt = b_wt + (size_t)l * 786432;
        k_gemm<256, 2><<<dim3(GR, 2), 256, 0, stream>>>(
            b_srcbf, wt + 0, bVal + l * 256, bVal + l * 256, BIG, nullptr, b_valbf, 256);
        k_gemm<256, 0><<<dim3(GR, 4), 256, 0, stream>>>(
            b_qbf, wt + 65536, bOff + l * 384, bAtt + l * 128, 384, b_oa, nullptr, 512);
        k_sample<<<dim3(NQ_), 256, 0, stream>>>(b_oa, b_valbf, b_aggbf);
        k_gemm<256, 0><<<dim3(GR, 2), 256, 0, stream>>>(
            b_aggbf, wt + 196608, bOut + l * 256, bOut + l * 256, BIG, b_tmp, nullptr, 256);
        k_add_ln<<<dim3(NQ_ / 4), 256, 0, stream>>>(b_src, b_tmp, ln1g + l * 256,
                                                    ln1b + l * 256, b_src, b_srcbf,
                                                    nullptr, nullptr);
        k_gemm<256, 1><<<dim3(GR, 8), 256, 0, stream>>>(
            b_srcbf, wt + 262144, bFf1 + l * 1024, bFf1 + l * 1024, BIG, nullptr, b_ffhbf, 1024);
        k_gemm<1024, 0><<<dim3(GR, 2), 256, 0, stream>>>(
            b_ffhbf, wt + 524288, bFf2 + l * 256, bFf2 + l * 256, BIG, b_tmp2, nullptr, 256);
        float* dst = (l == NL_ - 1) ? (float*)d_out : b_src;
        int last = (l == NL_ - 1);
        k_add_ln<<<dim3(NQ_ / 4), 256, 0, stream>>>(b_src, b_tmp2, ln2g + l * 256,
                                                    ln2b + l * 256, dst,
                                                    last ? nullptr : b_srcbf,
                                                    last ? nullptr : b_pos,
                                                    last ? nullptr : b_qbf);
    }
}